// Round 1
// baseline (243.035 us; speedup 1.0000x reference)
//
#include <hip/hip_runtime.h>
#include <hip/hip_bf16.h>
#include <stdint.h>

#define B_    4
#define NN    4096
#define DIN   512
#define DOUT  256
#define ALPHA_ 0.2f

typedef __attribute__((ext_vector_type(8))) short short8;
typedef __attribute__((ext_vector_type(4))) float f32x4;

typedef const __attribute__((address_space(1))) void gconst_void;
typedef __attribute__((address_space(3))) void lds_void;

__device__ __forceinline__ unsigned short f2bf(float x) {
    union { float f; uint32_t u; } v; v.f = x;
    uint32_t r = v.u + 0x7FFFu + ((v.u >> 16) & 1u);
    return (unsigned short)(r >> 16);
}
__device__ __forceinline__ float bf2f(unsigned short u) {
    union { uint32_t u; float f; } v; v.u = ((uint32_t)u) << 16;
    return v.f;
}

// ---------------- K0a: pack adj (int32 0/1) -> bitmask, 67MB -> 2MB ----------------
__global__ __launch_bounds__(256) void k_pack_adj(const int* __restrict__ adj,
                                                  uint32_t* __restrict__ bits) {
    int idx = blockIdx.x * 256 + threadIdx.x;
    unsigned long long m = __ballot(adj[idx] > 0);
    if ((threadIdx.x & 63) == 0)
        *reinterpret_cast<unsigned long long*>(bits + ((idx >> 6) << 1)) = m;
}

// ---------------- K0b: h fp32 -> bf16 ----------------
__global__ __launch_bounds__(256) void k_h_bf16(const float4* __restrict__ h,
                                                uint2* __restrict__ hb) {
    int idx = blockIdx.x * 256 + threadIdx.x;
    float4 v = h[idx];
    uint2 o;
    o.x = (uint32_t)f2bf(v.x) | ((uint32_t)f2bf(v.y) << 16);
    o.y = (uint32_t)f2bf(v.z) | ((uint32_t)f2bf(v.w) << 16);
    hb[idx] = o;
}

// ---------------- K0c: Ws (B,DIN,DOUT) fp32 -> WsT (B,DOUT,DIN) bf16 ----------------
__global__ __launch_bounds__(256) void k_wst(const float* __restrict__ Ws,
                                             unsigned short* __restrict__ wst) {
    int idx = blockIdx.x * 256 + threadIdx.x;      // B*DOUT*DIN total
    int k = idx & (DIN - 1);
    int o = (idx >> 9) & (DOUT - 1);
    int b = idx >> 17;
    wst[idx] = f2bf(Ws[((size_t)b * DIN + k) * DOUT + o]);
}

// ---------------- K1: WhT[b][d][m] = (h @ Ws)^T, bf16 MFMA ----------------
// block: 64 rows (n) x 256 cols (d), 4 waves each 64r x 64c, K tiled by 64
__global__ __launch_bounds__(256) void k_gemm1(const unsigned short* __restrict__ hb,
                                               const unsigned short* __restrict__ wst,
                                               unsigned short* __restrict__ wht) {
    __shared__ unsigned short Ah[64 * 64];    // [n][k] swizzled rows (128B)
    __shared__ unsigned short Bw[256 * 64];   // [d][k] swizzled rows (128B)
    const int tid = threadIdx.x;
    const int w = tid >> 6, lane = tid & 63;
    const int l15 = lane & 15, lhi = lane >> 4;
    const int b = blockIdx.y;
    const int n0 = blockIdx.x * 64;
    const unsigned short* hrow = hb + ((size_t)b * NN + n0) * DIN;
    const unsigned short* wrow = wst + (size_t)b * DOUT * DIN;

    f32x4 acc[4][4] = {};

    for (int kt = 0; kt < DIN / 64; ++kt) {
        const int k0 = kt * 64;
        #pragma unroll
        for (int it = 0; it < 2; ++it) {     // stage A: 8KB
            int q = it * 256 + tid;
            int row = q >> 3, c = q & 7;
            const unsigned short* src = hrow + (size_t)row * DIN + k0 + 8 * (c ^ (row & 7));
            char* dst = reinterpret_cast<char*>(Ah) + it * 4096 + w * 1024;
            __builtin_amdgcn_global_load_lds((gconst_void*)src, (lds_void*)dst, 16, 0, 0);
        }
        #pragma unroll
        for (int it = 0; it < 8; ++it) {     // stage B: 32KB
            int q = it * 256 + tid;
            int row = q >> 3, c = q & 7;
            const unsigned short* src = wrow + (size_t)row * DIN + k0 + 8 * (c ^ (row & 7));
            char* dst = reinterpret_cast<char*>(Bw) + it * 4096 + w * 1024;
            __builtin_amdgcn_global_load_lds((gconst_void*)src, (lds_void*)dst, 16, 0, 0);
        }
        __syncthreads();
        #pragma unroll
        for (int kk = 0; kk < 2; ++kk) {
            short8 af[4], bfr[4];
            #pragma unroll
            for (int rf = 0; rf < 4; ++rf) {
                int row = rf * 16 + l15;
                int off = row * 128 + ((kk * 64 + lhi * 16) ^ ((row & 7) << 4));
                af[rf] = *reinterpret_cast<const short8*>(reinterpret_cast<const char*>(Ah) + off);
            }
            #pragma unroll
            for (int cf = 0; cf < 4; ++cf) {
                int row = w * 64 + cf * 16 + l15;
                int off = row * 128 + ((kk * 64 + lhi * 16) ^ ((row & 7) << 4));
                bfr[cf] = *reinterpret_cast<const short8*>(reinterpret_cast<const char*>(Bw) + off);
            }
            #pragma unroll
            for (int rf = 0; rf < 4; ++rf)
                #pragma unroll
                for (int cf = 0; cf < 4; ++cf)
                    acc[rf][cf] = __builtin_amdgcn_mfma_f32_16x16x32_bf16(af[rf], bfr[cf], acc[rf][cf], 0, 0, 0);
        }
        __syncthreads();
    }
    unsigned short* wb = wht + (size_t)b * DOUT * NN;
    #pragma unroll
    for (int rf = 0; rf < 4; ++rf) {
        #pragma unroll
        for (int cf = 0; cf < 4; ++cf) {
            int d = w * 64 + cf * 16 + l15;
            int m = n0 + rf * 16 + lhi * 4;
            uint2 pk;
            pk.x = (uint32_t)f2bf(acc[rf][cf][0]) | ((uint32_t)f2bf(acc[rf][cf][1]) << 16);
            pk.y = (uint32_t)f2bf(acc[rf][cf][2]) | ((uint32_t)f2bf(acc[rf][cf][3]) << 16);
            *reinterpret_cast<uint2*>(wb + (size_t)d * NN + m) = pk;
        }
    }
}

// ---------------- K2: e1[n]=Wh[n,:].a1, e2[n]=Wh[n,:].a2 (from WhT) ----------------
__global__ __launch_bounds__(256) void k_e12(const unsigned short* __restrict__ wht,
                                             const float* __restrict__ a,
                                             float* __restrict__ e1, float* __restrict__ e2) {
    int n = blockIdx.x * 256 + threadIdx.x;
    int b = blockIdx.y;
    const unsigned short* wb = wht + (size_t)b * DOUT * NN + n;
    const float* ab = a + b * 2 * DOUT;
    float s1 = 0.f, s2 = 0.f;
    #pragma unroll 4
    for (int d = 0; d < DOUT; ++d) {
        float v = bf2f(wb[(size_t)d * NN]);
        s1 += v * ab[d];
        s2 += v * ab[DOUT + d];
    }
    e1[b * NN + n] = s1;
    e2[b * NN + n] = s2;
}

// ---------------- K3: per-row softmax stats (max, 1/sum) ----------------
__global__ __launch_bounds__(256) void k_stats(const float* __restrict__ e1,
                                               const float* __restrict__ e2,
                                               const uint32_t* __restrict__ bits,
                                               float* __restrict__ rowmax,
                                               float* __restrict__ invden) {
    __shared__ float e2s[NN];
    const int b = blockIdx.y;
    const int w = threadIdx.x >> 6, lane = threadIdx.x & 63;
    for (int i = threadIdx.x; i < NN; i += 256) e2s[i] = e2[b * NN + i];
    __syncthreads();
    const int n = blockIdx.x * 4 + w;
    const float e1n = e1[b * NN + n];
    const uint32_t* br = bits + (size_t)n * (NN / 32);
    float mx = -3.0e38f;
    for (int i = 0; i < 64; ++i) {
        unsigned long long wb = *reinterpret_cast<const unsigned long long*>(br + i * 2);
        float s = e1n + e2s[i * 64 + lane];
        float f = s > 0.f ? s : ALPHA_ * s;
        if ((wb >> lane) & 1ull) mx = fmaxf(mx, f);
    }
    #pragma unroll
    for (int off = 32; off > 0; off >>= 1) mx = fmaxf(mx, __shfl_xor(mx, off));
    float sum = 0.f;
    for (int i = 0; i < 64; ++i) {
        unsigned long long wb = *reinterpret_cast<const unsigned long long*>(br + i * 2);
        float s = e1n + e2s[i * 64 + lane];
        float f = s > 0.f ? s : ALPHA_ * s;
        if ((wb >> lane) & 1ull) sum += __expf(f - mx);
    }
    #pragma unroll
    for (int off = 32; off > 0; off >>= 1) sum += __shfl_xor(sum, off);
    if (lane == 0) {
        rowmax[b * NN + n] = mx;
        invden[b * NN + n] = 1.0f / sum;
    }
}

// ---------------- K4: h' = P @ Wh (P computed on the fly), ELU epilogue ----------------
// block: 32 rows x 256 cols, 4 waves each 32r x 64c, K (m) tiled by 64
__global__ __launch_bounds__(256, 2) void k_attn(const unsigned short* __restrict__ wht,
                                                 const uint32_t* __restrict__ bits,
                                                 const float* __restrict__ e1,
                                                 const float* __restrict__ e2,
                                                 const float* __restrict__ rowmax,
                                                 const float* __restrict__ invden,
                                                 float* __restrict__ out) {
    __shared__ unsigned short Bw[256 * 64];  // WhT tile [d][m], swizzled 128B rows (32KB)
    __shared__ unsigned short Pt[32 * 64];   // P tile  [r][m], swizzled 128B rows (4KB)
    __shared__ float e2s[NN];                // 16KB

    const int tid = threadIdx.x;
    const int w = tid >> 6, lane = tid & 63;
    const int l15 = lane & 15, lhi = lane >> 4;
    const int b = blockIdx.y;
    const int n0 = blockIdx.x * 32;

    for (int i = tid; i < NN; i += 256) e2s[i] = e2[b * NN + i];

    const int pr = tid >> 3, pc = tid & 7;
    const int gn = n0 + pr;
    const float pe1 = e1[b * NN + gn];
    const float pmx = rowmax[b * NN + gn];
    const float pid = invden[b * NN + gn];
    const uint8_t* brow = reinterpret_cast<const uint8_t*>(bits) + (size_t)gn * (NN / 8);
    const unsigned short* wb = wht + (size_t)b * DOUT * NN;

    f32x4 acc[2][4] = {};
    __syncthreads();

    for (int kt = 0; kt < NN / 64; ++kt) {
        const int m0 = kt * 64;
        #pragma unroll
        for (int it = 0; it < 8; ++it) {     // stage WhT tile: 32KB
            int q = it * 256 + tid;
            int row = q >> 3, c = q & 7;
            const unsigned short* src = wb + (size_t)row * NN + m0 + 8 * (c ^ (row & 7));
            char* dst = reinterpret_cast<char*>(Bw) + it * 4096 + w * 1024;
            __builtin_amdgcn_global_load_lds((gconst_void*)src, (lds_void*)dst, 16, 0, 0);
        }
        // compute P chunk: 8 values per thread, written swizzled as one b128
        uint32_t bb = brow[(m0 >> 3) + pc];
        union { short8 v; unsigned short u[8]; } pk;
        #pragma unroll
        for (int j = 0; j < 8; ++j) {
            float s = pe1 + e2s[m0 + pc * 8 + j];
            float f = s > 0.f ? s : ALPHA_ * s;
            float p = ((bb >> j) & 1u) ? __expf(f - pmx) * pid : 0.f;
            pk.u[j] = f2bf(p);
        }
        *reinterpret_cast<short8*>(reinterpret_cast<char*>(Pt) + pr * 128 +
                                   ((pc * 16) ^ ((pr & 7) << 4))) = pk.v;
        __syncthreads();
        #pragma unroll
        for (int kk = 0; kk < 2; ++kk) {
            short8 af[2], bfr[4];
            #pragma unroll
            for (int rf = 0; rf < 2; ++rf) {
                int row = rf * 16 + l15;
                int off = row * 128 + ((kk * 64 + lhi * 16) ^ ((row & 7) << 4));
                af[rf] = *reinterpret_cast<const short8*>(reinterpret_cast<const char*>(Pt) + off);
            }
            #pragma unroll
            for (int cf = 0; cf < 4; ++cf) {
                int row = w * 64 + cf * 16 + l15;
                int off = row * 128 + ((kk * 64 + lhi * 16) ^ ((row & 7) << 4));
                bfr[cf] = *reinterpret_cast<const short8*>(reinterpret_cast<const char*>(Bw) + off);
            }
            #pragma unroll
            for (int rf = 0; rf < 2; ++rf)
                #pragma unroll
                for (int cf = 0; cf < 4; ++cf)
                    acc[rf][cf] = __builtin_amdgcn_mfma_f32_16x16x32_bf16(af[rf], bfr[cf], acc[rf][cf], 0, 0, 0);
        }
        __syncthreads();
    }
    // epilogue: ELU + store fp32
    #pragma unroll
    for (int rf = 0; rf < 2; ++rf) {
        #pragma unroll
        for (int cf = 0; cf < 4; ++cf) {
            int d = w * 64 + cf * 16 + l15;
            int m = n0 + rf * 16 + lhi * 4;
            #pragma unroll
            for (int j = 0; j < 4; ++j) {
                float x = acc[rf][cf][j];
                x = x > 0.f ? x : (__expf(x) - 1.f);
                out[((size_t)b * NN + m + j) * DOUT + d] = x;
            }
        }
    }
}

extern "C" void kernel_launch(void* const* d_in, const int* in_sizes, int n_in,
                              void* d_out, int out_size, void* d_ws, size_t ws_size,
                              hipStream_t stream) {
    (void)in_sizes; (void)n_in; (void)out_size; (void)ws_size;
    const float* h   = (const float*)d_in[0];
    const int*   adj = (const int*)d_in[1];
    const float* Ws  = (const float*)d_in[2];
    const float* a   = (const float*)d_in[3];
    float* out = (float*)d_out;

    char* ws = (char*)d_ws;
    unsigned short* hb  = (unsigned short*)(ws);              // 16,777,216 B
    unsigned short* wst = (unsigned short*)(ws + 16777216);   //  1,048,576 B
    unsigned short* wht = (unsigned short*)(ws + 17825792);   //  8,388,608 B
    float* e1  = (float*)(ws + 26214400);                     //     65,536 B
    float* e2  = (float*)(ws + 26279936);                     //     65,536 B
    float* rmx = (float*)(ws + 26345472);                     //     65,536 B
    float* idn = (float*)(ws + 26411008);                     //     65,536 B
    uint32_t* bits = (uint32_t*)(ws + 26476544);              //  2,097,152 B -> 28,573,696 total

    k_pack_adj<<<dim3(NN * NN / 256), dim3(256), 0, stream>>>(adj, bits);
    k_h_bf16<<<dim3(B_ * NN * DIN / 1024), dim3(256), 0, stream>>>((const float4*)h, (uint2*)hb);
    k_wst<<<dim3(B_ * DOUT * DIN / 256), dim3(256), 0, stream>>>(Ws, wst);
    k_gemm1<<<dim3(NN / 64, B_), dim3(256), 0, stream>>>(hb, wst, wht);
    k_e12<<<dim3(NN / 256, B_), dim3(256), 0, stream>>>(wht, a, e1, e2);
    k_stats<<<dim3(NN / 4, B_), dim3(256), 0, stream>>>(e1, e2, bits, rmx, idn);
    k_attn<<<dim3(NN / 32, B_), dim3(256), 0, stream>>>(wht, bits, e1, e2, rmx, idn, out);
}

// Round 2
// 202.849 us; speedup vs baseline: 1.1981x; 1.1981x over previous
//
#include <hip/hip_runtime.h>
#include <hip/hip_bf16.h>
#include <stdint.h>

#define B_    4
#define NN    4096
#define DIN   512
#define DOUT  256
#define ALPHA_ 0.2f

typedef __attribute__((ext_vector_type(8))) short short8;
typedef __attribute__((ext_vector_type(4))) float f32x4;

typedef const __attribute__((address_space(1))) void gconst_void;
typedef __attribute__((address_space(3))) void lds_void;

__device__ __forceinline__ unsigned short f2bf(float x) {
    union { float f; uint32_t u; } v; v.f = x;
    uint32_t r = v.u + 0x7FFFu + ((v.u >> 16) & 1u);
    return (unsigned short)(r >> 16);
}
__device__ __forceinline__ float bf2f(unsigned short u) {
    union { uint32_t u; float f; } v; v.u = ((uint32_t)u) << 16;
    return v.f;
}

// ---------------- K0a: pack adj (int32 0/1) -> bitmask, 67MB -> 2MB ----------------
__global__ __launch_bounds__(256) void k_pack_adj(const int* __restrict__ adj,
                                                  uint32_t* __restrict__ bits) {
    int idx = blockIdx.x * 256 + threadIdx.x;
    unsigned long long m = __ballot(adj[idx] > 0);
    if ((threadIdx.x & 63) == 0)
        *reinterpret_cast<unsigned long long*>(bits + ((idx >> 6) << 1)) = m;
}

// ---------------- K0b: h fp32 -> bf16 ----------------
__global__ __launch_bounds__(256) void k_h_bf16(const float4* __restrict__ h,
                                                uint2* __restrict__ hb) {
    int idx = blockIdx.x * 256 + threadIdx.x;
    float4 v = h[idx];
    uint2 o;
    o.x = (uint32_t)f2bf(v.x) | ((uint32_t)f2bf(v.y) << 16);
    o.y = (uint32_t)f2bf(v.z) | ((uint32_t)f2bf(v.w) << 16);
    hb[idx] = o;
}

// ---------------- K0c: Ws (B,DIN,DOUT) fp32 -> WsT (B,DOUT,DIN) bf16 ----------------
__global__ __launch_bounds__(256) void k_wst(const float* __restrict__ Ws,
                                             unsigned short* __restrict__ wst) {
    int idx = blockIdx.x * 256 + threadIdx.x;      // B*DOUT*DIN total
    int k = idx & (DIN - 1);
    int o = (idx >> 9) & (DOUT - 1);
    int b = idx >> 17;
    wst[idx] = f2bf(Ws[((size_t)b * DIN + k) * DOUT + o]);
}

// ---------------- K1: WhT[b][d][m] = (h @ Ws)^T, bf16 MFMA ----------------
__global__ __launch_bounds__(256) void k_gemm1(const unsigned short* __restrict__ hb,
                                               const unsigned short* __restrict__ wst,
                                               unsigned short* __restrict__ wht) {
    __shared__ unsigned short Ah[64 * 64];    // [n][k] swizzled rows (128B)
    __shared__ unsigned short Bw[256 * 64];   // [d][k] swizzled rows (128B)
    const int tid = threadIdx.x;
    const int w = tid >> 6, lane = tid & 63;
    const int l15 = lane & 15, lhi = lane >> 4;
    const int b = blockIdx.y;
    const int n0 = blockIdx.x * 64;
    const unsigned short* hrow = hb + ((size_t)b * NN + n0) * DIN;
    const unsigned short* wrow = wst + (size_t)b * DOUT * DIN;

    f32x4 acc[4][4] = {};

    for (int kt = 0; kt < DIN / 64; ++kt) {
        const int k0 = kt * 64;
        #pragma unroll
        for (int it = 0; it < 2; ++it) {     // stage A: 8KB
            int q = it * 256 + tid;
            int row = q >> 3, c = q & 7;
            const unsigned short* src = hrow + (size_t)row * DIN + k0 + 8 * (c ^ (row & 7));
            char* dst = reinterpret_cast<char*>(Ah) + it * 4096 + w * 1024;
            __builtin_amdgcn_global_load_lds((gconst_void*)src, (lds_void*)dst, 16, 0, 0);
        }
        #pragma unroll
        for (int it = 0; it < 8; ++it) {     // stage B: 32KB
            int q = it * 256 + tid;
            int row = q >> 3, c = q & 7;
            const unsigned short* src = wrow + (size_t)row * DIN + k0 + 8 * (c ^ (row & 7));
            char* dst = reinterpret_cast<char*>(Bw) + it * 4096 + w * 1024;
            __builtin_amdgcn_global_load_lds((gconst_void*)src, (lds_void*)dst, 16, 0, 0);
        }
        __syncthreads();
        #pragma unroll
        for (int kk = 0; kk < 2; ++kk) {
            short8 af[4], bfr[4];
            #pragma unroll
            for (int rf = 0; rf < 4; ++rf) {
                int row = rf * 16 + l15;
                int off = row * 128 + ((kk * 64 + lhi * 16) ^ ((row & 7) << 4));
                af[rf] = *reinterpret_cast<const short8*>(reinterpret_cast<const char*>(Ah) + off);
            }
            #pragma unroll
            for (int cf = 0; cf < 4; ++cf) {
                int row = w * 64 + cf * 16 + l15;
                int off = row * 128 + ((kk * 64 + lhi * 16) ^ ((row & 7) << 4));
                bfr[cf] = *reinterpret_cast<const short8*>(reinterpret_cast<const char*>(Bw) + off);
            }
            #pragma unroll
            for (int rf = 0; rf < 4; ++rf)
                #pragma unroll
                for (int cf = 0; cf < 4; ++cf)
                    acc[rf][cf] = __builtin_amdgcn_mfma_f32_16x16x32_bf16(af[rf], bfr[cf], acc[rf][cf], 0, 0, 0);
        }
        __syncthreads();
    }
    unsigned short* wb = wht + (size_t)b * DOUT * NN;
    #pragma unroll
    for (int rf = 0; rf < 4; ++rf) {
        #pragma unroll
        for (int cf = 0; cf < 4; ++cf) {
            int d = w * 64 + cf * 16 + l15;
            int m = n0 + rf * 16 + lhi * 4;
            uint2 pk;
            pk.x = (uint32_t)f2bf(acc[rf][cf][0]) | ((uint32_t)f2bf(acc[rf][cf][1]) << 16);
            pk.y = (uint32_t)f2bf(acc[rf][cf][2]) | ((uint32_t)f2bf(acc[rf][cf][3]) << 16);
            *reinterpret_cast<uint2*>(wb + (size_t)d * NN + m) = pk;
        }
    }
}

// ---------------- K2: e1[n]=Wh[n,:].a1, e2[n]=Wh[n,:].a2 (from WhT) ----------------
__global__ __launch_bounds__(256) void k_e12(const unsigned short* __restrict__ wht,
                                             const float* __restrict__ a,
                                             float* __restrict__ e1, float* __restrict__ e2) {
    int n = blockIdx.x * 256 + threadIdx.x;
    int b = blockIdx.y;
    const unsigned short* wb = wht + (size_t)b * DOUT * NN + n;
    const float* ab = a + b * 2 * DOUT;
    float s1 = 0.f, s2 = 0.f;
    #pragma unroll 4
    for (int d = 0; d < DOUT; ++d) {
        float v = bf2f(wb[(size_t)d * NN]);
        s1 += v * ab[d];
        s2 += v * ab[DOUT + d];
    }
    e1[b * NN + n] = s1;
    e2[b * NN + n] = s2;
}

// ---------------- K3: per-row lse = rowmax + log(sum) ----------------
__global__ __launch_bounds__(256) void k_stats(const float* __restrict__ e1,
                                               const float* __restrict__ e2,
                                               const uint32_t* __restrict__ bits,
                                               float* __restrict__ lse) {
    __shared__ float e2s[NN];
    const int b = blockIdx.y;
    const int w = threadIdx.x >> 6, lane = threadIdx.x & 63;
    for (int i = threadIdx.x; i < NN; i += 256) e2s[i] = e2[b * NN + i];
    __syncthreads();
    const int n = blockIdx.x * 4 + w;
    const float e1n = e1[b * NN + n];
    const uint32_t* br = bits + (size_t)n * (NN / 32);
    float mx = -3.0e38f;
    for (int i = 0; i < 64; ++i) {
        unsigned long long wb = *reinterpret_cast<const unsigned long long*>(br + i * 2);
        float s = e1n + e2s[i * 64 + lane];
        float f = fmaxf(s, ALPHA_ * s);
        if ((wb >> lane) & 1ull) mx = fmaxf(mx, f);
    }
    #pragma unroll
    for (int off = 32; off > 0; off >>= 1) mx = fmaxf(mx, __shfl_xor(mx, off));
    float sum = 0.f;
    for (int i = 0; i < 64; ++i) {
        unsigned long long wb = *reinterpret_cast<const unsigned long long*>(br + i * 2);
        float s = e1n + e2s[i * 64 + lane];
        float f = fmaxf(s, ALPHA_ * s);
        if ((wb >> lane) & 1ull) sum += __expf(f - mx);
    }
    #pragma unroll
    for (int off = 32; off > 0; off >>= 1) sum += __shfl_xor(sum, off);
    if (lane == 0) lse[b * NN + n] = mx + __logf(sum);
}

// ---------------- K4: h' = P @ Wh (P on the fly), single-barrier 2-phase pipeline ----
// block: 64 n-rows x 128 d-cols, 4 waves = 2(n) x 2(d), each 32n x 64d (acc 2x4)
__global__ __launch_bounds__(256, 2) void k_attn(const unsigned short* __restrict__ wht,
                                                 const uint32_t* __restrict__ bits,
                                                 const float* __restrict__ e1,
                                                 const float* __restrict__ e2,
                                                 const float* __restrict__ lse,
                                                 float* __restrict__ out) {
    __shared__ unsigned short Bw[2 * 128 * 64];  // WhT tile dbuf, swizzled 128B rows (32KB)
    __shared__ unsigned short Pt[2 * 64 * 64];   // P tile dbuf, swizzled 128B rows (16KB)

    const int tid = threadIdx.x;
    const int w = tid >> 6, lane = tid & 63;
    const int l15 = lane & 15, lhi = lane >> 4;
    const int wn = w >> 1, wd = w & 1;

    // XCD-aware bijective swizzle: 512 blocks, 8 XCDs -> each XCD covers 1/2 batch
    const int bid = blockIdx.x;
    const int wg = ((bid & 7) << 6) | (bid >> 3);
    const int b  = wg >> 7;
    const int r  = wg & 127;
    const int d0 = (r & 1) << 7;      // 0 or 128
    const int n0 = (r >> 1) << 6;     // 64-row chunk

    // P-compute thread mapping: pr = row (0..63), pc = 16-col group (0..3)
    const int pr = tid >> 2, pc = tid & 3;
    const int gn = n0 + pr;
    const float pe1  = e1[b * NN + gn];
    const float plse = lse[b * NN + gn];
    const uint8_t* browb = reinterpret_cast<const uint8_t*>(bits) + (size_t)gn * (NN / 8);
    const float* e2g = e2 + b * NN;
    const unsigned short* wb = wht + (size_t)b * DOUT * NN;

    f32x4 acc[2][4] = {};

    // ---- prologue: stage tile 0, compute P(0) ----
    #pragma unroll
    for (int it = 0; it < 4; ++it) {
        int q = it * 256 + tid;
        int row = q >> 3, c = q & 7;
        const unsigned short* src = wb + (size_t)(d0 + row) * NN + 8 * (c ^ (row & 7));
        char* dst = reinterpret_cast<char*>(Bw) + it * 4096 + w * 1024;
        __builtin_amdgcn_global_load_lds((gconst_void*)src, (lds_void*)dst, 16, 0, 0);
    }
    {
        unsigned int bb = *reinterpret_cast<const unsigned short*>(browb + pc * 2);
        const float4* e2p = reinterpret_cast<const float4*>(e2g + pc * 16);
        float4 ea = e2p[0], eb = e2p[1], ec = e2p[2], ed = e2p[3];
        float pv[16];
        pv[0]=ea.x; pv[1]=ea.y; pv[2]=ea.z; pv[3]=ea.w;
        pv[4]=eb.x; pv[5]=eb.y; pv[6]=eb.z; pv[7]=eb.w;
        pv[8]=ec.x; pv[9]=ec.y; pv[10]=ec.z; pv[11]=ec.w;
        pv[12]=ed.x; pv[13]=ed.y; pv[14]=ed.z; pv[15]=ed.w;
        #pragma unroll
        for (int j = 0; j < 16; ++j) {
            float s = pe1 + pv[j];
            float f = fmaxf(s, ALPHA_ * s);
            float p = __expf(f - plse);
            pv[j] = ((bb >> j) & 1u) ? p : 0.f;
        }
        union { short8 v; uint32_t u[4]; } k0, k1;
        #pragma unroll
        for (int i = 0; i < 4; ++i) {
            union { __hip_bfloat162 h; uint32_t u; } c0, c1;
            c0.h = __float22bfloat162_rn(float2{pv[2*i], pv[2*i+1]});
            c1.h = __float22bfloat162_rn(float2{pv[8+2*i], pv[8+2*i+1]});
            k0.u[i] = c0.u; k1.u[i] = c1.u;
        }
        char* base = reinterpret_cast<char*>(Pt);
        *reinterpret_cast<short8*>(base + pr * 128 + ((pc * 32)      ^ ((pr & 7) << 4))) = k0.v;
        *reinterpret_cast<short8*>(base + pr * 128 + ((pc * 32 + 16) ^ ((pr & 7) << 4))) = k1.v;
    }
    __syncthreads();

    // ---- main loop: 1 barrier per tile, stage(t+1) overlapped with MFMA(t) ----
    for (int t = 0; t < NN / 64; ++t) {
        const int cur = t & 1;
        unsigned int bregN = 0;
        float4 ea, eb, ec, ed;
        if (t < NN / 64 - 1) {
            const int m1 = (t + 1) * 64;
            #pragma unroll
            for (int it = 0; it < 4; ++it) {
                int q = it * 256 + tid;
                int row = q >> 3, c = q & 7;
                const unsigned short* src = wb + (size_t)(d0 + row) * NN + m1 + 8 * (c ^ (row & 7));
                char* dst = reinterpret_cast<char*>(Bw) + (cur ^ 1) * 16384 + it * 4096 + w * 1024;
                __builtin_amdgcn_global_load_lds((gconst_void*)src, (lds_void*)dst, 16, 0, 0);
            }
            bregN = *reinterpret_cast<const unsigned short*>(browb + (m1 >> 3) + pc * 2);
            const float4* e2p = reinterpret_cast<const float4*>(e2g + m1 + pc * 16);
            ea = e2p[0]; eb = e2p[1]; ec = e2p[2]; ed = e2p[3];
        }
        // MFMA phase on buffers [cur]
        #pragma unroll
        for (int kk = 0; kk < 2; ++kk) {
            short8 af[2], bfr[4];
            #pragma unroll
            for (int rf = 0; rf < 2; ++rf) {
                int row = wn * 32 + rf * 16 + l15;
                int off = row * 128 + ((kk * 64 + lhi * 16) ^ ((row & 7) << 4));
                af[rf] = *reinterpret_cast<const short8*>(
                    reinterpret_cast<const char*>(Pt) + cur * 8192 + off);
            }
            #pragma unroll
            for (int cf = 0; cf < 4; ++cf) {
                int row = wd * 64 + cf * 16 + l15;
                int off = row * 128 + ((kk * 64 + lhi * 16) ^ ((row & 7) << 4));
                bfr[cf] = *reinterpret_cast<const short8*>(
                    reinterpret_cast<const char*>(Bw) + cur * 16384 + off);
            }
            #pragma unroll
            for (int rf = 0; rf < 2; ++rf)
                #pragma unroll
                for (int cf = 0; cf < 4; ++cf)
                    acc[rf][cf] = __builtin_amdgcn_mfma_f32_16x16x32_bf16(af[rf], bfr[cf], acc[rf][cf], 0, 0, 0);
        }
        if (t < NN / 64 - 1) {
            // P(t+1) from prefetched regs (exp overlaps staging latency)
            float pv[16];
            pv[0]=ea.x; pv[1]=ea.y; pv[2]=ea.z; pv[3]=ea.w;
            pv[4]=eb.x; pv[5]=eb.y; pv[6]=eb.z; pv[7]=eb.w;
            pv[8]=ec.x; pv[9]=ec.y; pv[10]=ec.z; pv[11]=ec.w;
            pv[12]=ed.x; pv[13]=ed.y; pv[14]=ed.z; pv[15]=ed.w;
            #pragma unroll
            for (int j = 0; j < 16; ++j) {
                float s = pe1 + pv[j];
                float f = fmaxf(s, ALPHA_ * s);
                float p = __expf(f - plse);
                pv[j] = ((bregN >> j) & 1u) ? p : 0.f;
            }
            union { short8 v; uint32_t u[4]; } k0, k1;
            #pragma unroll
            for (int i = 0; i < 4; ++i) {
                union { __hip_bfloat162 h; uint32_t u; } c0, c1;
                c0.h = __float22bfloat162_rn(float2{pv[2*i], pv[2*i+1]});
                c1.h = __float22bfloat162_rn(float2{pv[8+2*i], pv[8+2*i+1]});
                k0.u[i] = c0.u; k1.u[i] = c1.u;
            }
            char* base = reinterpret_cast<char*>(Pt) + (cur ^ 1) * 8192;
            *reinterpret_cast<short8*>(base + pr * 128 + ((pc * 32)      ^ ((pr & 7) << 4))) = k0.v;
            *reinterpret_cast<short8*>(base + pr * 128 + ((pc * 32 + 16) ^ ((pr & 7) << 4))) = k1.v;
            __syncthreads();
        }
    }
    // epilogue: ELU + store fp32
    #pragma unroll
    for (int rf = 0; rf < 2; ++rf) {
        #pragma unroll
        for (int cf = 0; cf < 4; ++cf) {
            int d = d0 + wd * 64 + cf * 16 + l15;
            int m = n0 + wn * 32 + rf * 16 + lhi * 4;
            #pragma unroll
            for (int j = 0; j < 4; ++j) {
                float x = acc[rf][cf][j];
                x = x > 0.f ? x : (__expf(x) - 1.f);
                out[((size_t)b * NN + m + j) * DOUT + d] = x;
            }
        }
    }
}

extern "C" void kernel_launch(void* const* d_in, const int* in_sizes, int n_in,
                              void* d_out, int out_size, void* d_ws, size_t ws_size,
                              hipStream_t stream) {
    (void)in_sizes; (void)n_in; (void)out_size; (void)ws_size;
    const float* h   = (const float*)d_in[0];
    const int*   adj = (const int*)d_in[1];
    const float* Ws  = (const float*)d_in[2];
    const float* a   = (const float*)d_in[3];
    float* out = (float*)d_out;

    char* ws = (char*)d_ws;
    unsigned short* hb  = (unsigned short*)(ws);              // 16,777,216 B
    unsigned short* wst = (unsigned short*)(ws + 16777216);   //  1,048,576 B
    unsigned short* wht = (unsigned short*)(ws + 17825792);   //  8,388,608 B
    float* e1  = (float*)(ws + 26214400);                     //     65,536 B
    float* e2  = (float*)(ws + 26279936);                     //     65,536 B
    float* lse = (float*)(ws + 26345472);                     //     65,536 B
    uint32_t* bits = (uint32_t*)(ws + 26476544);              //  2,097,152 B

    k_pack_adj<<<dim3(NN * NN / 256), dim3(256), 0, stream>>>(adj, bits);
    k_h_bf16<<<dim3(B_ * NN * DIN / 1024), dim3(256), 0, stream>>>((const float4*)h, (uint2*)hb);
    k_wst<<<dim3(B_ * DOUT * DIN / 256), dim3(256), 0, stream>>>(Ws, wst);
    k_gemm1<<<dim3(NN / 64, B_), dim3(256), 0, stream>>>(hb, wst, wht);
    k_e12<<<dim3(NN / 256, B_), dim3(256), 0, stream>>>(wht, a, e1, e2);
    k_stats<<<dim3(NN / 4, B_), dim3(256), 0, stream>>>(e1, e2, bits, lse);
    k_attn<<<dim3(NN / 64 * (DOUT / 128) * B_), dim3(256), 0, stream>>>(wht, bits, e1, e2, lse, out);
}

// Round 3
// 131.250 us; speedup vs baseline: 1.8517x; 1.5455x over previous
//
#include <hip/hip_runtime.h>
#include <hip/hip_bf16.h>
#include <stdint.h>

#define B_    4
#define NN    4096
#define DIN   512
#define DOUT  256
#define ALPHA_ 0.2f

typedef __attribute__((ext_vector_type(8))) short short8;
typedef __attribute__((ext_vector_type(4))) float f32x4;

typedef const __attribute__((address_space(1))) void gconst_void;
typedef __attribute__((address_space(3))) void lds_void;

__device__ __forceinline__ unsigned short f2bf(float x) {
    union { float f; uint32_t u; } v; v.f = x;
    uint32_t r = v.u + 0x7FFFu + ((v.u >> 16) & 1u);
    return (unsigned short)(r >> 16);
}
__device__ __forceinline__ float bf2f(unsigned short u) {
    union { uint32_t u; float f; } v; v.u = ((uint32_t)u) << 16;
    return v.f;
}

// ---------------- K_prep: pack adj -> bits | h fp32->bf16 | Ws -> WsT bf16 ----------
// sections by blockIdx: [0,65536) pack, [65536,73728) h, [73728,75776) wst
__global__ __launch_bounds__(256) void k_prep(const int* __restrict__ adj,
                                              const float4* __restrict__ h4,
                                              const float* __restrict__ Ws,
                                              uint32_t* __restrict__ bits,
                                              uint2* __restrict__ hb,
                                              unsigned short* __restrict__ wst) {
    const int gid = blockIdx.x;
    const int tid = threadIdx.x;
    if (gid < 65536) {                       // pack adj: 67MB -> 2MB
        int idx = gid * 256 + tid;
        unsigned long long m = __ballot(adj[idx] > 0);
        if ((tid & 63) == 0)
            *reinterpret_cast<unsigned long long*>(bits + ((idx >> 6) << 1)) = m;
    } else if (gid < 73728) {                // h -> bf16 (float4 granularity)
        int idx = (gid - 65536) * 256 + tid;
        float4 v = h4[idx];
        uint2 o;
        o.x = (uint32_t)f2bf(v.x) | ((uint32_t)f2bf(v.y) << 16);
        o.y = (uint32_t)f2bf(v.z) | ((uint32_t)f2bf(v.w) << 16);
        hb[idx] = o;
    } else {                                 // Ws (B,DIN,DOUT) -> WsT (B,DOUT,DIN) bf16
        int idx = (gid - 73728) * 256 + tid;
        int k = idx & (DIN - 1);
        int o = (idx >> 9) & (DOUT - 1);
        int b = idx >> 17;
        wst[idx] = f2bf(Ws[((size_t)b * DIN + k) * DOUT + o]);
    }
}

// ---------------- K1: WhT[b][d][m] = (h @ Ws)^T + fused e1/e2 epilogue --------------
// block: 64 rows (n) x 256 cols (d), 4 waves each 64r x 64c, K tiled by 64
__global__ __launch_bounds__(256) void k_gemm1(const unsigned short* __restrict__ hb,
                                               const unsigned short* __restrict__ wst,
                                               const float* __restrict__ a,
                                               unsigned short* __restrict__ wht,
                                               float* __restrict__ e1,
                                               float* __restrict__ e2) {
    __shared__ unsigned short Ah[64 * 64];    // [n][k] swizzled rows (128B)
    __shared__ unsigned short Bw[256 * 64];   // [d][k] swizzled rows (128B)
    __shared__ float e1s[64], e2s[64];
    const int tid = threadIdx.x;
    const int w = tid >> 6, lane = tid & 63;
    const int l15 = lane & 15, lhi = lane >> 4;
    const int b = blockIdx.y;
    const int n0 = blockIdx.x * 64;
    const unsigned short* hrow = hb + ((size_t)b * NN + n0) * DIN;
    const unsigned short* wrow = wst + (size_t)b * DOUT * DIN;

    if (tid < 64) { e1s[tid] = 0.f; e2s[tid] = 0.f; }

    f32x4 acc[4][4] = {};

    for (int kt = 0; kt < DIN / 64; ++kt) {
        const int k0 = kt * 64;
        #pragma unroll
        for (int it = 0; it < 2; ++it) {     // stage A: 8KB
            int q = it * 256 + tid;
            int row = q >> 3, c = q & 7;
            const unsigned short* src = hrow + (size_t)row * DIN + k0 + 8 * (c ^ (row & 7));
            char* dst = reinterpret_cast<char*>(Ah) + it * 4096 + w * 1024;
            __builtin_amdgcn_global_load_lds((gconst_void*)src, (lds_void*)dst, 16, 0, 0);
        }
        #pragma unroll
        for (int it = 0; it < 8; ++it) {     // stage B: 32KB
            int q = it * 256 + tid;
            int row = q >> 3, c = q & 7;
            const unsigned short* src = wrow + (size_t)row * DIN + k0 + 8 * (c ^ (row & 7));
            char* dst = reinterpret_cast<char*>(Bw) + it * 4096 + w * 1024;
            __builtin_amdgcn_global_load_lds((gconst_void*)src, (lds_void*)dst, 16, 0, 0);
        }
        __syncthreads();
        #pragma unroll
        for (int kk = 0; kk < 2; ++kk) {
            short8 af[4], bfr[4];
            #pragma unroll
            for (int rf = 0; rf < 4; ++rf) {
                int row = rf * 16 + l15;
                int off = row * 128 + ((kk * 64 + lhi * 16) ^ ((row & 7) << 4));
                af[rf] = *reinterpret_cast<const short8*>(reinterpret_cast<const char*>(Ah) + off);
            }
            #pragma unroll
            for (int cf = 0; cf < 4; ++cf) {
                int row = w * 64 + cf * 16 + l15;
                int off = row * 128 + ((kk * 64 + lhi * 16) ^ ((row & 7) << 4));
                bfr[cf] = *reinterpret_cast<const short8*>(reinterpret_cast<const char*>(Bw) + off);
            }
            #pragma unroll
            for (int rf = 0; rf < 4; ++rf)
                #pragma unroll
                for (int cf = 0; cf < 4; ++cf)
                    acc[rf][cf] = __builtin_amdgcn_mfma_f32_16x16x32_bf16(af[rf], bfr[cf], acc[rf][cf], 0, 0, 0);
        }
        __syncthreads();
    }
    // WhT write (bf16, transposed)
    unsigned short* wb = wht + (size_t)b * DOUT * NN;
    #pragma unroll
    for (int rf = 0; rf < 4; ++rf) {
        #pragma unroll
        for (int cf = 0; cf < 4; ++cf) {
            int d = w * 64 + cf * 16 + l15;
            int m = n0 + rf * 16 + lhi * 4;
            uint2 pk;
            pk.x = (uint32_t)f2bf(acc[rf][cf][0]) | ((uint32_t)f2bf(acc[rf][cf][1]) << 16);
            pk.y = (uint32_t)f2bf(acc[rf][cf][2]) | ((uint32_t)f2bf(acc[rf][cf][3]) << 16);
            *reinterpret_cast<uint2*>(wb + (size_t)d * NN + m) = pk;
        }
    }
    // fused e1/e2: e1[m] = sum_d Wh[m][d]*a1[d] (fp32 acc, shfl-reduce over l15)
    const float* ab = a + b * 2 * DOUT;
    float a1v[4], a2v[4];
    #pragma unroll
    for (int cf = 0; cf < 4; ++cf) {
        int d = w * 64 + cf * 16 + l15;
        a1v[cf] = ab[d];
        a2v[cf] = ab[DOUT + d];
    }
    #pragma unroll
    for (int rf = 0; rf < 4; ++rf) {
        #pragma unroll
        for (int j = 0; j < 4; ++j) {
            float p1 = 0.f, p2 = 0.f;
            #pragma unroll
            for (int cf = 0; cf < 4; ++cf) {
                p1 = fmaf(acc[rf][cf][j], a1v[cf], p1);
                p2 = fmaf(acc[rf][cf][j], a2v[cf], p2);
            }
            #pragma unroll
            for (int msk = 1; msk < 16; msk <<= 1) {
                p1 += __shfl_xor(p1, msk);
                p2 += __shfl_xor(p2, msk);
            }
            if (l15 == 0) {
                atomicAdd(&e1s[rf * 16 + lhi * 4 + j], p1);
                atomicAdd(&e2s[rf * 16 + lhi * 4 + j], p2);
            }
        }
    }
    __syncthreads();
    if (tid < 64) {
        e1[b * NN + n0 + tid] = e1s[tid];
        e2[b * NN + n0 + tid] = e2s[tid];
    }
}

// ---------------- K4: h' = softmax(P)@Wh, unnormalized-accumulate + epilogue scale --
// block: 32 n-rows x 256 d-cols, 4 waves (wd=0..3) each 32n x 64d (acc 2x4)
// grid 512 = 2 blocks/CU; no stats pass: psum accumulated in-loop, 1/psum at end
__global__ __launch_bounds__(256, 2) void k_attn(const unsigned short* __restrict__ wht,
                                                 const uint32_t* __restrict__ bits,
                                                 const float* __restrict__ e1,
                                                 const float* __restrict__ e2,
                                                 float* __restrict__ out) {
    __shared__ unsigned short Bw[2 * 256 * 64];  // WhT tile dbuf, swizzled 128B rows (64KB)
    __shared__ unsigned short Pt[2 * 32 * 64];   // P tile dbuf, swizzled 128B rows (8KB)
    __shared__ float sums[32];

    const int tid = threadIdx.x;
    const int w = tid >> 6, lane = tid & 63;
    const int l15 = lane & 15, lhi = lane >> 4;

    // XCD-aware bijective swizzle: 512 blocks % 8 == 0
    const int bid = blockIdx.x;
    const int wg = ((bid & 7) << 6) | (bid >> 3);
    const int b  = wg >> 7;
    const int n0 = (wg & 127) << 5;   // 32-row chunk

    // P-compute mapping: pr = row (0..31), pc = 8-col group (0..7)
    const int pr = tid >> 3, pc = tid & 7;
    const int gn = n0 + pr;
    const float r1 = e1[b * NN + gn];
    const float r2 = ALPHA_ * r1;
    const uint8_t* browb = reinterpret_cast<const uint8_t*>(bits) + (size_t)gn * (NN / 8);
    const float* e2g = e2 + b * NN;
    const unsigned short* wb = wht + (size_t)b * DOUT * NN;

    f32x4 acc[2][4] = {};
    float psum = 0.f;

    // ---- prologue: stage tile 0, compute P(0) ----
    #pragma unroll
    for (int it = 0; it < 8; ++it) {
        int q = it * 256 + tid;
        int row = q >> 3, c = q & 7;
        const unsigned short* src = wb + (size_t)row * NN + 8 * (c ^ (row & 7));
        char* dst = reinterpret_cast<char*>(Bw) + it * 4096 + w * 1024;
        __builtin_amdgcn_global_load_lds((gconst_void*)src, (lds_void*)dst, 16, 0, 0);
    }
    {
        uint32_t bb = browb[pc];
        const float4* ep = reinterpret_cast<const float4*>(e2g + pc * 8);
        float4 ea = ep[0], eb = ep[1];
        float pv[8] = {ea.x, ea.y, ea.z, ea.w, eb.x, eb.y, eb.z, eb.w};
        #pragma unroll
        for (int j = 0; j < 8; ++j) {
            float s = r1 + pv[j];
            float t = fmaf(ALPHA_, pv[j], r2);
            float p = __expf(fmaxf(s, t));
            uint32_t msk = (uint32_t)(((int32_t)(bb << (31 - j))) >> 31);
            union { float f; uint32_t u; } pu; pu.f = p; pu.u &= msk;
            pv[j] = pu.f;
            psum += pv[j];
        }
        union { short8 v; uint32_t u[4]; } k0;
        #pragma unroll
        for (int i = 0; i < 4; ++i) {
            union { __hip_bfloat162 h; uint32_t u; } c0;
            c0.h = __float22bfloat162_rn(float2{pv[2 * i], pv[2 * i + 1]});
            k0.u[i] = c0.u;
        }
        *reinterpret_cast<short8*>(reinterpret_cast<char*>(Pt) + pr * 128 +
                                   ((pc * 16) ^ ((pr & 7) << 4))) = k0.v;
    }
    __syncthreads();

    // ---- main loop: 1 barrier/tile, stage(t+1) + P(t+1) overlapped with MFMA(t) ----
    #pragma unroll 2
    for (int t = 0; t < NN / 64; ++t) {
        const int cur = t & 1;
        uint32_t bbN = 0;
        float4 ea, eb;
        if (t < NN / 64 - 1) {
            const int m1 = (t + 1) * 64;
            #pragma unroll
            for (int it = 0; it < 8; ++it) {
                int q = it * 256 + tid;
                int row = q >> 3, c = q & 7;
                const unsigned short* src = wb + (size_t)row * NN + m1 + 8 * (c ^ (row & 7));
                char* dst = reinterpret_cast<char*>(Bw) + (cur ^ 1) * 32768 + it * 4096 + w * 1024;
                __builtin_amdgcn_global_load_lds((gconst_void*)src, (lds_void*)dst, 16, 0, 0);
            }
            bbN = browb[(m1 >> 3) + pc];
            const float4* ep = reinterpret_cast<const float4*>(e2g + m1 + pc * 8);
            ea = ep[0]; eb = ep[1];
        }
        // MFMA phase on buffers [cur]
        __builtin_amdgcn_s_setprio(1);
        #pragma unroll
        for (int kk = 0; kk < 2; ++kk) {
            short8 af[2], bfr[4];
            #pragma unroll
            for (int rf = 0; rf < 2; ++rf) {
                int row = rf * 16 + l15;
                int off = row * 128 + ((kk * 64 + lhi * 16) ^ ((row & 7) << 4));
                af[rf] = *reinterpret_cast<const short8*>(
                    reinterpret_cast<const char*>(Pt) + cur * 4096 + off);
            }
            #pragma unroll
            for (int cf = 0; cf < 4; ++cf) {
                int row = w * 64 + cf * 16 + l15;
                int off = row * 128 + ((kk * 64 + lhi * 16) ^ ((row & 7) << 4));
                bfr[cf] = *reinterpret_cast<const short8*>(
                    reinterpret_cast<const char*>(Bw) + cur * 32768 + off);
            }
            #pragma unroll
            for (int rf = 0; rf < 2; ++rf)
                #pragma unroll
                for (int cf = 0; cf < 4; ++cf)
                    acc[rf][cf] = __builtin_amdgcn_mfma_f32_16x16x32_bf16(af[rf], bfr[cf], acc[rf][cf], 0, 0, 0);
        }
        __builtin_amdgcn_s_setprio(0);
        if (t < NN / 64 - 1) {
            float pv[8] = {ea.x, ea.y, ea.z, ea.w, eb.x, eb.y, eb.z, eb.w};
            #pragma unroll
            for (int j = 0; j < 8; ++j) {
                float s = r1 + pv[j];
                float tt = fmaf(ALPHA_, pv[j], r2);
                float p = __expf(fmaxf(s, tt));
                uint32_t msk = (uint32_t)(((int32_t)(bbN << (31 - j))) >> 31);
                union { float f; uint32_t u; } pu; pu.f = p; pu.u &= msk;
                pv[j] = pu.f;
                psum += pv[j];
            }
            union { short8 v; uint32_t u[4]; } k0;
            #pragma unroll
            for (int i = 0; i < 4; ++i) {
                union { __hip_bfloat162 h; uint32_t u; } c0;
                c0.h = __float22bfloat162_rn(float2{pv[2 * i], pv[2 * i + 1]});
                k0.u[i] = c0.u;
            }
            *reinterpret_cast<short8*>(reinterpret_cast<char*>(Pt) + (cur ^ 1) * 4096 + pr * 128 +
                                       ((pc * 16) ^ ((pr & 7) << 4))) = k0.v;
            __syncthreads();
        }
    }
    // ---- epilogue: row-sum reduce, scale by 1/sum, ELU, store ----
    psum += __shfl_xor(psum, 1);
    psum += __shfl_xor(psum, 2);
    psum += __shfl_xor(psum, 4);
    if ((tid & 7) == 0) sums[pr] = psum;
    __syncthreads();
    #pragma unroll
    for (int rf = 0; rf < 2; ++rf) {
        #pragma unroll
        for (int cf = 0; cf < 4; ++cf) {
            int d = w * 64 + cf * 16 + l15;
            #pragma unroll
            for (int j = 0; j < 4; ++j) {
                int lr = rf * 16 + lhi * 4 + j;
                float x = acc[rf][cf][j] / sums[lr];
                x = x > 0.f ? x : (__expf(x) - 1.f);
                out[((size_t)b * NN + n0 + lr) * DOUT + d] = x;
            }
        }
    }
}

extern "C" void kernel_launch(void* const* d_in, const int* in_sizes, int n_in,
                              void* d_out, int out_size, void* d_ws, size_t ws_size,
                              hipStream_t stream) {
    (void)in_sizes; (void)n_in; (void)out_size; (void)ws_size;
    const float* h   = (const float*)d_in[0];
    const int*   adj = (const int*)d_in[1];
    const float* Ws  = (const float*)d_in[2];
    const float* a   = (const float*)d_in[3];
    float* out = (float*)d_out;

    char* ws = (char*)d_ws;
    unsigned short* hb  = (unsigned short*)(ws);              // 16,777,216 B
    unsigned short* wst = (unsigned short*)(ws + 16777216);   //  1,048,576 B
    unsigned short* wht = (unsigned short*)(ws + 17825792);   //  8,388,608 B
    float* e1  = (float*)(ws + 26214400);                     //     65,536 B
    float* e2  = (float*)(ws + 26279936);                     //     65,536 B
    uint32_t* bits = (uint32_t*)(ws + 26476544);              //  2,097,152 B

    k_prep<<<dim3(75776), dim3(256), 0, stream>>>(adj, (const float4*)h, Ws,
                                                  bits, (uint2*)hb, wst);
    k_gemm1<<<dim3(NN / 64, B_), dim3(256), 0, stream>>>(hb, wst, a, wht, e1, e2);
    k_attn<<<dim3(512), dim3(256), 0, stream>>>(wht, bits, e1, e2, out);
}